// Round 1
// baseline (202.427 us; speedup 1.0000x reference)
//
#include <hip/hip_runtime.h>
#include <hip/hip_bf16.h>

// Problem constants
#define VD 160           // vol D=H=W
#define OD 128           // output crop size
#define CROP0 16         // (160-128)/2
#define FSZ 11           // cropped field size
#define RAWSZ 15         // raw field size
#define NBATCH 4

// ---------------------------------------------------------------------------
// Kernel 1: Rodrigues + theta (N=4, trivial)
// ---------------------------------------------------------------------------
__global__ void prep_theta(const float* __restrict__ rot,
                           const float* __restrict__ scale,
                           const float* __restrict__ shift,
                           float* __restrict__ theta) {
    int n = threadIdx.x;
    if (n >= NBATCH) return;
    float rx = rot[n*3+0], ry = rot[n*3+1], rz = rot[n*3+2];
    float t2 = rx*rx + ry*ry + rz*rz;
    const float eps = 1e-6f;
    float th = sqrtf(fmaxf(t2, eps));
    float inv = 1.0f / (th + eps);
    float wx = rx*inv, wy = ry*inv, wz = rz*inv;
    float c = cosf(th), s = sinf(th), k = 1.0f - c;
    float R[9];
    if (t2 > eps) {
        R[0] = c + wx*wx*k;      R[1] = wx*wy*k - wz*s;  R[2] = wy*s + wx*wz*k;
        R[3] = wz*s + wx*wy*k;   R[4] = c + wy*wy*k;     R[5] = -wx*s + wy*wz*k;
        R[6] = -wy*s + wx*wz*k;  R[7] = wx*s + wy*wz*k;  R[8] = c + wz*wz*k;
    } else {
        R[0] = 1.0f; R[1] = -rz;  R[2] = ry;
        R[3] = rz;   R[4] = 1.0f; R[5] = -rx;
        R[6] = -ry;  R[7] = rx;   R[8] = 1.0f;
    }
    // A = R * scale (scale multiplies columns); theta = [A | shift]
    for (int i = 0; i < 3; ++i) {
        for (int j = 0; j < 3; ++j)
            theta[n*12 + i*4 + j] = R[i*3 + j] * scale[n*3 + j];
        theta[n*12 + i*4 + 3] = shift[n*3 + i];
    }
}

// ---------------------------------------------------------------------------
// Kernel 2: displacement field prep. One block per channel (dz,dy,dx).
// d = (raw-0.5)*2*ALPHA = (raw-0.5)*4; 4x box-smooth 5^3 with edge padding
// (separable into 1D clamp-index mean passes); crop center 11^3 -> ws.
// ---------------------------------------------------------------------------
__global__ __launch_bounds__(256) void field_smooth(
        const float* __restrict__ dz, const float* __restrict__ dy,
        const float* __restrict__ dx, float* __restrict__ fields) {
    __shared__ float bufA[RAWSZ*RAWSZ*RAWSZ];
    __shared__ float bufB[RAWSZ*RAWSZ*RAWSZ];
    const int tid = threadIdx.x;
    const int chan = blockIdx.x;
    const float* raw = (chan == 0) ? dz : (chan == 1) ? dy : dx;
    const int NTOT = RAWSZ*RAWSZ*RAWSZ;   // 3375

    for (int i = tid; i < NTOT; i += 256)
        bufA[i] = (raw[i] - 0.5f) * 4.0f;
    __syncthreads();

    float* src = bufA;
    float* dst = bufB;
    for (int it = 0; it < 4; ++it) {
        for (int ax = 0; ax < 3; ++ax) {
            const int stride = (ax == 0) ? RAWSZ*RAWSZ : (ax == 1) ? RAWSZ : 1;
            for (int i = tid; i < NTOT; i += 256) {
                int z = i / (RAWSZ*RAWSZ);
                int r = i % (RAWSZ*RAWSZ);
                int y = r / RAWSZ;
                int x = r % RAWSZ;
                int c = (ax == 0) ? z : (ax == 1) ? y : x;
                float s = 0.0f;
                #pragma unroll
                for (int t = -2; t <= 2; ++t) {
                    int cc = min(max(c + t, 0), RAWSZ - 1);
                    s += src[i + (cc - c) * stride];
                }
                dst[i] = s * 0.2f;
            }
            __syncthreads();
            float* tmp = src; src = dst; dst = tmp;
        }
    }
    // crop [2:13]^3 -> 11^3
    for (int i = tid; i < FSZ*FSZ*FSZ; i += 256) {
        int z = i / (FSZ*FSZ);
        int r = i % (FSZ*FSZ);
        int y = r / FSZ;
        int x = r % FSZ;
        fields[chan*FSZ*FSZ*FSZ + i] =
            src[(z+2)*RAWSZ*RAWSZ + (y+2)*RAWSZ + (x+2)];
    }
}

// ---------------------------------------------------------------------------
// Kernel 3: main sampler. One thread per output voxel.
// block = 256 (ow=128 x oh=2), grid = (64, 128, 4).
// ---------------------------------------------------------------------------
__device__ __forceinline__ void resize_coord(int m, int& i0, int& i1, float& w) {
    // src = (m+0.5)*(11/160) - 0.5, clipped to [0,10]
    float s = fmaf((float)m + 0.5f, (float)FSZ / (float)VD, -0.5f);
    s = fminf(fmaxf(s, 0.0f), (float)(FSZ - 1));
    float f = floorf(s);
    i0 = (int)f;
    i1 = min(i0 + 1, FSZ - 1);
    w = s - f;
}

__global__ __launch_bounds__(256) void sample_kernel(
        const float* __restrict__ vol, const float* __restrict__ theta,
        const float* __restrict__ fields, float* __restrict__ out) {
    const int tx = threadIdx.x;
    const int ow = tx & 127;
    const int oh = (blockIdx.x << 1) | (tx >> 7);
    const int od = blockIdx.y;
    const int n  = blockIdx.z;

    const int w_ = ow + CROP0;
    const int h_ = oh + CROP0;
    const int d_ = od + CROP0;

    // normalized coords over the FULL 160^3 grid
    const float x = fmaf(2.0f * (float)w_ + 1.0f, 1.0f / (float)VD, -1.0f);
    const float y = fmaf(2.0f * (float)h_ + 1.0f, 1.0f / (float)VD, -1.0f);
    const float z = fmaf(2.0f * (float)d_ + 1.0f, 1.0f / (float)VD, -1.0f);

    // displacement: trilinear from 11^3 fields
    int zi0, zi1, yi0, yi1, xi0, xi1;
    float zw, yw, xw;
    resize_coord(d_, zi0, zi1, zw);
    resize_coord(h_, yi0, yi1, yw);
    resize_coord(w_, xi0, xi1, xw);
    const float wz0 = 1.0f - zw, wy0 = 1.0f - yw, wx0 = 1.0f - xw;
    const float w000 = wz0*wy0*wx0, w001 = wz0*wy0*xw;
    const float w010 = wz0*yw*wx0,  w011 = wz0*yw*xw;
    const float w100 = zw*wy0*wx0,  w101 = zw*wy0*xw;
    const float w110 = zw*yw*wx0,   w111 = zw*yw*xw;
    const int b00 = zi0*121 + yi0*11, b01 = zi0*121 + yi1*11;
    const int b10 = zi1*121 + yi0*11, b11 = zi1*121 + yi1*11;

    float disp[3];
    #pragma unroll
    for (int c = 0; c < 3; ++c) {
        const float* f = fields + c * (FSZ*FSZ*FSZ);
        disp[c] = f[b00+xi0]*w000 + f[b00+xi1]*w001
                + f[b01+xi0]*w010 + f[b01+xi1]*w011
                + f[b10+xi0]*w100 + f[b10+xi1]*w101
                + f[b11+xi0]*w110 + f[b11+xi1]*w111;
    }

    const float* th = theta + n*12;
    const float gx = th[0]*x + th[1]*y + th[2]*z  + th[3]  + disp[0];
    const float gy = th[4]*x + th[5]*y + th[6]*z  + th[7]  + disp[1];
    const float gz = th[8]*x + th[9]*y + th[10]*z + th[11] + disp[2];

    // unnormalize: ((g+1)*160 - 1)*0.5 = 80*g + 79.5
    const float xs = fmaf(gx, 80.0f, 79.5f);
    const float ys = fmaf(gy, 80.0f, 79.5f);
    const float zs = fmaf(gz, 80.0f, 79.5f);

    const float x0f = floorf(xs), y0f = floorf(ys), z0f = floorf(zs);
    const float fx = xs - x0f, fy = ys - y0f, fz = zs - z0f;
    const int ix0 = (int)x0f, iy0 = (int)y0f, iz0 = (int)z0f;
    const int ix1 = ix0 + 1,  iy1 = iy0 + 1,  iz1 = iz0 + 1;

    const float* v = vol + (size_t)n * VD*VD*VD;
    auto g = [&](int zi, int yi, int xi) -> float {
        bool ok = ((unsigned)zi < (unsigned)VD) & ((unsigned)yi < (unsigned)VD)
                & ((unsigned)xi < (unsigned)VD);
        int zc = min(max(zi, 0), VD-1);
        int yc = min(max(yi, 0), VD-1);
        int xc = min(max(xi, 0), VD-1);
        float val = v[((size_t)zc*VD + yc)*VD + xc];
        return ok ? val : 0.0f;
    };

    const float fz0 = 1.0f - fz, fy0 = 1.0f - fy, fx0 = 1.0f - fx;
    float r = g(iz0, iy0, ix0) * (fz0*fy0*fx0)
            + g(iz0, iy0, ix1) * (fz0*fy0*fx)
            + g(iz0, iy1, ix0) * (fz0*fy*fx0)
            + g(iz0, iy1, ix1) * (fz0*fy*fx)
            + g(iz1, iy0, ix0) * (fz*fy0*fx0)
            + g(iz1, iy0, ix1) * (fz*fy0*fx)
            + g(iz1, iy1, ix0) * (fz*fy*fx0)
            + g(iz1, iy1, ix1) * (fz*fy*fx);

    out[(((size_t)n*OD + od)*OD + oh)*OD + ow] = r;
}

// ---------------------------------------------------------------------------
extern "C" void kernel_launch(void* const* d_in, const int* in_sizes, int n_in,
                              void* d_out, int out_size, void* d_ws, size_t ws_size,
                              hipStream_t stream) {
    const float* vol   = (const float*)d_in[0];
    const float* rot   = (const float*)d_in[1];
    const float* scale = (const float*)d_in[2];
    const float* shift = (const float*)d_in[3];
    const float* dz    = (const float*)d_in[4];
    const float* dy    = (const float*)d_in[5];
    const float* dx    = (const float*)d_in[6];
    float* out = (float*)d_out;

    float* ws     = (float*)d_ws;
    float* theta  = ws;         // 4*12 = 48 floats
    float* fields = ws + 48;    // 3*1331 floats

    prep_theta<<<1, 64, 0, stream>>>(rot, scale, shift, theta);
    field_smooth<<<3, 256, 0, stream>>>(dz, dy, dx, fields);
    dim3 grid(OD/2, OD, NBATCH);
    sample_kernel<<<grid, 256, 0, stream>>>(vol, theta, fields, out);
}

// Round 2
// 193.249 us; speedup vs baseline: 1.0475x; 1.0475x over previous
//
#include <hip/hip_runtime.h>
#include <hip/hip_bf16.h>

// Problem constants
#define VD 160           // vol D=H=W
#define OD 128           // output crop size
#define CROP0 16         // (160-128)/2
#define FSZ 11           // cropped field size
#define RAWSZ 15         // raw field size
#define NBATCH 4

// ---------------------------------------------------------------------------
// Kernel 1: field prep (blocks 0..2) + Rodrigues/theta (block 3).
// d = (raw-0.5)*4; 4x separable 5-tap clamp-mean passes; crop center 11^3.
// ---------------------------------------------------------------------------
__global__ __launch_bounds__(256) void prep_kernel(
        const float* __restrict__ rot, const float* __restrict__ scale,
        const float* __restrict__ shift,
        const float* __restrict__ dz, const float* __restrict__ dy,
        const float* __restrict__ dx,
        float* __restrict__ theta, float* __restrict__ fields) {
    const int tid = threadIdx.x;
    const int chan = blockIdx.x;

    if (chan == 3) {
        // ----- theta -----
        int n = tid;
        if (n >= NBATCH) return;
        float rx = rot[n*3+0], ry = rot[n*3+1], rz = rot[n*3+2];
        float t2 = rx*rx + ry*ry + rz*rz;
        const float eps = 1e-6f;
        float th = sqrtf(fmaxf(t2, eps));
        float inv = 1.0f / (th + eps);
        float wx = rx*inv, wy = ry*inv, wz = rz*inv;
        float c = cosf(th), s = sinf(th), k = 1.0f - c;
        float R[9];
        if (t2 > eps) {
            R[0] = c + wx*wx*k;      R[1] = wx*wy*k - wz*s;  R[2] = wy*s + wx*wz*k;
            R[3] = wz*s + wx*wy*k;   R[4] = c + wy*wy*k;     R[5] = -wx*s + wy*wz*k;
            R[6] = -wy*s + wx*wz*k;  R[7] = wx*s + wy*wz*k;  R[8] = c + wz*wz*k;
        } else {
            R[0] = 1.0f; R[1] = -rz;  R[2] = ry;
            R[3] = rz;   R[4] = 1.0f; R[5] = -rx;
            R[6] = -ry;  R[7] = rx;   R[8] = 1.0f;
        }
        for (int i = 0; i < 3; ++i) {
            for (int j = 0; j < 3; ++j)
                theta[n*12 + i*4 + j] = R[i*3 + j] * scale[n*3 + j];
            theta[n*12 + i*4 + 3] = shift[n*3 + i];
        }
        return;
    }

    // ----- field smooth -----
    __shared__ float bufA[RAWSZ*RAWSZ*RAWSZ];
    __shared__ float bufB[RAWSZ*RAWSZ*RAWSZ];
    const float* raw = (chan == 0) ? dz : (chan == 1) ? dy : dx;
    const int NTOT = RAWSZ*RAWSZ*RAWSZ;   // 3375

    for (int i = tid; i < NTOT; i += 256)
        bufA[i] = (raw[i] - 0.5f) * 4.0f;
    __syncthreads();

    float* src = bufA;
    float* dst = bufB;
    for (int it = 0; it < 4; ++it) {
        for (int ax = 0; ax < 3; ++ax) {
            const int stride = (ax == 0) ? RAWSZ*RAWSZ : (ax == 1) ? RAWSZ : 1;
            for (int i = tid; i < NTOT; i += 256) {
                int z = i / (RAWSZ*RAWSZ);
                int r = i % (RAWSZ*RAWSZ);
                int y = r / RAWSZ;
                int x = r % RAWSZ;
                int c = (ax == 0) ? z : (ax == 1) ? y : x;
                float s = 0.0f;
                #pragma unroll
                for (int t = -2; t <= 2; ++t) {
                    int cc = min(max(c + t, 0), RAWSZ - 1);
                    s += src[i + (cc - c) * stride];
                }
                dst[i] = s * 0.2f;
            }
            __syncthreads();
            float* tmp = src; src = dst; dst = tmp;
        }
    }
    for (int i = tid; i < FSZ*FSZ*FSZ; i += 256) {
        int z = i / (FSZ*FSZ);
        int r = i % (FSZ*FSZ);
        int y = r / FSZ;
        int x = r % FSZ;
        fields[chan*FSZ*FSZ*FSZ + i] =
            src[(z+2)*RAWSZ*RAWSZ + (y+2)*RAWSZ + (x+2)];
    }
}

// ---------------------------------------------------------------------------
// resize helper: src = (m+0.5)*(11/160) - 0.5, clipped to [0,10]
// ---------------------------------------------------------------------------
__device__ __forceinline__ void resize_coord(int m, int& i0, int& i1, float& w) {
    float s = fmaf((float)m + 0.5f, (float)FSZ / (float)VD, -0.5f);
    s = fminf(fmaxf(s, 0.0f), (float)(FSZ - 1));
    float f = floorf(s);
    i0 = (int)f;
    i1 = min(i0 + 1, FSZ - 1);
    w = s - f;
}

// ---------------------------------------------------------------------------
// Kernel 2: main sampler. Block = 512 threads covering (w=128, oh=2, od=2).
// grid = (OD/2, OD/2, NBATCH). Per-block LDS: e[oh_i][od_i][c][xi] = the
// (z,y)-bilinear of the displacement field at each of 11 x-knots, x80.
// ---------------------------------------------------------------------------
__global__ __launch_bounds__(512) void sample_kernel(
        const float* __restrict__ vol, const float* __restrict__ theta,
        const float* __restrict__ fields, float* __restrict__ out) {
    __shared__ float e[2][2][3][12];   // [oh_i][od_i][chan][xi] (pad 12)

    const int tid  = threadIdx.x;
    const int ow   = tid & 127;
    const int oh_i = (tid >> 7) & 1;
    const int od_i = tid >> 8;
    const int oh   = (blockIdx.x << 1) | oh_i;
    const int od   = (blockIdx.y << 1) | od_i;
    const int n    = blockIdx.z;

    // ---- fill e: 2*2*3*11 = 132 items ----
    if (tid < 132) {
        int t = tid;
        int eoh = t / 66;  t -= eoh * 66;
        int eod = t / 33;  t -= eod * 33;
        int c   = t / 11;
        int xi  = t - c * 11;
        int d_ = ((blockIdx.y << 1) | eod) + CROP0;
        int h_ = ((blockIdx.x << 1) | eoh) + CROP0;
        int zi0, zi1, yi0, yi1;
        float zw, yw;
        resize_coord(d_, zi0, zi1, zw);
        resize_coord(h_, yi0, yi1, yw);
        const float* f = fields + c * (FSZ*FSZ*FSZ);
        float v = f[zi0*121 + yi0*11 + xi] * ((1.0f-zw)*(1.0f-yw))
                + f[zi0*121 + yi1*11 + xi] * ((1.0f-zw)*yw)
                + f[zi1*121 + yi0*11 + xi] * (zw*(1.0f-yw))
                + f[zi1*121 + yi1*11 + xi] * (zw*yw);
        e[eoh][eod][c][xi] = v * 80.0f;   // pre-scale to voxel units
    }
    __syncthreads();

    const int w_ = ow + CROP0;
    const int h_ = oh + CROP0;
    const int d_ = od + CROP0;

    // normalized coords over the FULL 160^3 grid
    const float x = fmaf(2.0f * (float)w_ + 1.0f, 1.0f / (float)VD, -1.0f);
    const float y = fmaf(2.0f * (float)h_ + 1.0f, 1.0f / (float)VD, -1.0f);
    const float z = fmaf(2.0f * (float)d_ + 1.0f, 1.0f / (float)VD, -1.0f);

    // displacement (voxel units, x80 already): 1D lerp over x-knots
    int xi0, xi1; float xw;
    resize_coord(w_, xi0, xi1, xw);
    const float* eb = &e[oh_i][od_i][0][0];
    const float d80x = eb[      xi0] + (eb[      xi1] - eb[      xi0]) * xw;
    const float d80y = eb[12  + xi0] + (eb[12  + xi1] - eb[12  + xi0]) * xw;
    const float d80z = eb[24  + xi0] + (eb[24  + xi1] - eb[24  + xi0]) * xw;

    const float* th = theta + n*12;
    const float gx = th[0]*x + th[1]*y + th[2]*z  + th[3];
    const float gy = th[4]*x + th[5]*y + th[6]*z  + th[7];
    const float gz = th[8]*x + th[9]*y + th[10]*z + th[11];

    // unnormalize: 80*g + 79.5, plus displacement already in voxel units
    const float xs = fmaf(gx, 80.0f, 79.5f) + d80x;
    const float ys = fmaf(gy, 80.0f, 79.5f) + d80y;
    const float zs = fmaf(gz, 80.0f, 79.5f) + d80z;

    const float x0f = floorf(xs), y0f = floorf(ys), z0f = floorf(zs);
    const float fx = xs - x0f, fy = ys - y0f, fz = zs - z0f;
    const int ix0 = (int)x0f, iy0 = (int)y0f, iz0 = (int)z0f;
    const int ix1 = ix0 + 1,  iy1 = iy0 + 1,  iz1 = iz0 + 1;

    // fold validity into per-axis weights; clamp indices once
    const float wx0 = ((unsigned)ix0 < (unsigned)VD) ? (1.0f - fx) : 0.0f;
    const float wx1 = ((unsigned)ix1 < (unsigned)VD) ? fx          : 0.0f;
    const float wy0 = ((unsigned)iy0 < (unsigned)VD) ? (1.0f - fy) : 0.0f;
    const float wy1 = ((unsigned)iy1 < (unsigned)VD) ? fy          : 0.0f;
    const float wz0 = ((unsigned)iz0 < (unsigned)VD) ? (1.0f - fz) : 0.0f;
    const float wz1 = ((unsigned)iz1 < (unsigned)VD) ? fz          : 0.0f;

    const int xc0 = min(max(ix0, 0), VD-1), xc1 = min(max(ix1, 0), VD-1);
    const int yc0 = min(max(iy0, 0), VD-1), yc1 = min(max(iy1, 0), VD-1);
    const int zc0 = min(max(iz0, 0), VD-1), zc1 = min(max(iz1, 0), VD-1);

    const float* v = vol + (size_t)n * (VD*VD*VD);
    const float* p00 = v + (zc0*VD + yc0)*VD;
    const float* p01 = v + (zc0*VD + yc1)*VD;
    const float* p10 = v + (zc1*VD + yc0)*VD;
    const float* p11 = v + (zc1*VD + yc1)*VD;

    const float r00 = p00[xc0]*wx0 + p00[xc1]*wx1;
    const float r01 = p01[xc0]*wx0 + p01[xc1]*wx1;
    const float r10 = p10[xc0]*wx0 + p10[xc1]*wx1;
    const float r11 = p11[xc0]*wx0 + p11[xc1]*wx1;

    const float r = (r00*wy0 + r01*wy1)*wz0 + (r10*wy0 + r11*wy1)*wz1;

    __builtin_nontemporal_store(r, &out[(((size_t)n*OD + od)*OD + oh)*OD + ow]);
}

// ---------------------------------------------------------------------------
extern "C" void kernel_launch(void* const* d_in, const int* in_sizes, int n_in,
                              void* d_out, int out_size, void* d_ws, size_t ws_size,
                              hipStream_t stream) {
    const float* vol   = (const float*)d_in[0];
    const float* rot   = (const float*)d_in[1];
    const float* scale = (const float*)d_in[2];
    const float* shift = (const float*)d_in[3];
    const float* dz    = (const float*)d_in[4];
    const float* dy    = (const float*)d_in[5];
    const float* dx    = (const float*)d_in[6];
    float* out = (float*)d_out;

    float* ws     = (float*)d_ws;
    float* theta  = ws;         // 4*12 = 48 floats
    float* fields = ws + 48;    // 3*1331 floats

    prep_kernel<<<4, 256, 0, stream>>>(rot, scale, shift, dz, dy, dx,
                                       theta, fields);
    dim3 grid(OD/2, OD/2, NBATCH);
    sample_kernel<<<grid, 512, 0, stream>>>(vol, theta, fields, out);
}

// Round 3
// 188.768 us; speedup vs baseline: 1.0724x; 1.0237x over previous
//
#include <hip/hip_runtime.h>
#include <hip/hip_bf16.h>

// Problem constants
#define VD 160           // vol D=H=W
#define OD 128           // output crop size
#define CROP0 16         // (160-128)/2
#define FSZ 11           // cropped field size
#define RAWSZ 15         // raw field size
#define NBATCH 4
#define ODQ 4            // outputs per thread along od

// ---------------------------------------------------------------------------
// Kernel 1: field prep (blocks 0..2) + Rodrigues/theta (block 3).
// ---------------------------------------------------------------------------
__global__ __launch_bounds__(256) void prep_kernel(
        const float* __restrict__ rot, const float* __restrict__ scale,
        const float* __restrict__ shift,
        const float* __restrict__ dz, const float* __restrict__ dy,
        const float* __restrict__ dx,
        float* __restrict__ theta, float* __restrict__ fields) {
    const int tid = threadIdx.x;
    const int chan = blockIdx.x;

    if (chan == 3) {
        int n = tid;
        if (n >= NBATCH) return;
        float rx = rot[n*3+0], ry = rot[n*3+1], rz = rot[n*3+2];
        float t2 = rx*rx + ry*ry + rz*rz;
        const float eps = 1e-6f;
        float th = sqrtf(fmaxf(t2, eps));
        float inv = 1.0f / (th + eps);
        float wx = rx*inv, wy = ry*inv, wz = rz*inv;
        float c = cosf(th), s = sinf(th), k = 1.0f - c;
        float R[9];
        if (t2 > eps) {
            R[0] = c + wx*wx*k;      R[1] = wx*wy*k - wz*s;  R[2] = wy*s + wx*wz*k;
            R[3] = wz*s + wx*wy*k;   R[4] = c + wy*wy*k;     R[5] = -wx*s + wy*wz*k;
            R[6] = -wy*s + wx*wz*k;  R[7] = wx*s + wy*wz*k;  R[8] = c + wz*wz*k;
        } else {
            R[0] = 1.0f; R[1] = -rz;  R[2] = ry;
            R[3] = rz;   R[4] = 1.0f; R[5] = -rx;
            R[6] = -ry;  R[7] = rx;   R[8] = 1.0f;
        }
        for (int i = 0; i < 3; ++i) {
            for (int j = 0; j < 3; ++j)
                theta[n*12 + i*4 + j] = R[i*3 + j] * scale[n*3 + j];
            theta[n*12 + i*4 + 3] = shift[n*3 + i];
        }
        return;
    }

    __shared__ float bufA[RAWSZ*RAWSZ*RAWSZ];
    __shared__ float bufB[RAWSZ*RAWSZ*RAWSZ];
    const float* raw = (chan == 0) ? dz : (chan == 1) ? dy : dx;
    const int NTOT = RAWSZ*RAWSZ*RAWSZ;   // 3375

    for (int i = tid; i < NTOT; i += 256)
        bufA[i] = (raw[i] - 0.5f) * 4.0f;
    __syncthreads();

    float* src = bufA;
    float* dst = bufB;
    for (int it = 0; it < 4; ++it) {
        for (int ax = 0; ax < 3; ++ax) {
            const int stride = (ax == 0) ? RAWSZ*RAWSZ : (ax == 1) ? RAWSZ : 1;
            for (int i = tid; i < NTOT; i += 256) {
                int z = i / (RAWSZ*RAWSZ);
                int r = i % (RAWSZ*RAWSZ);
                int y = r / RAWSZ;
                int x = r % RAWSZ;
                int c = (ax == 0) ? z : (ax == 1) ? y : x;
                float s = 0.0f;
                #pragma unroll
                for (int t = -2; t <= 2; ++t) {
                    int cc = min(max(c + t, 0), RAWSZ - 1);
                    s += src[i + (cc - c) * stride];
                }
                dst[i] = s * 0.2f;
            }
            __syncthreads();
            float* tmp = src; src = dst; dst = tmp;
        }
    }
    for (int i = tid; i < FSZ*FSZ*FSZ; i += 256) {
        int z = i / (FSZ*FSZ);
        int r = i % (FSZ*FSZ);
        int y = r / FSZ;
        int x = r % FSZ;
        fields[chan*FSZ*FSZ*FSZ + i] =
            src[(z+2)*RAWSZ*RAWSZ + (y+2)*RAWSZ + (x+2)];
    }
}

// ---------------------------------------------------------------------------
// resize helper: src = (m+0.5)*(11/160) - 0.5, clipped to [0,10]
// ---------------------------------------------------------------------------
__device__ __forceinline__ void resize_coord(int m, int& i0, int& i1, float& w) {
    float s = fmaf((float)m + 0.5f, (float)FSZ / (float)VD, -0.5f);
    s = fminf(fmaxf(s, 0.0f), (float)(FSZ - 1));
    float f = floorf(s);
    i0 = (int)f;
    i1 = min(i0 + 1, FSZ - 1);
    w = s - f;
}

// ---------------------------------------------------------------------------
// Kernel 2: main sampler. Block = 512 threads covering (ow=128, oh=2, od=8);
// each thread computes ODQ=4 consecutive od outputs -> 32 independent global
// loads in flight per wave (MLP), setup amortized 4x.
// grid = (OD/2, OD/8, NBATCH).
// e[oh_i][od_l][c][xi]: (z,y)-bilinear of disp field at 11 x-knots, x80.
// ---------------------------------------------------------------------------
__global__ __launch_bounds__(512, 4) void sample_kernel(
        const float* __restrict__ vol, const float* __restrict__ theta,
        const float* __restrict__ fields, float* __restrict__ out) {
    __shared__ float e[2][8][3][12];

    const int tid  = threadIdx.x;
    const int ow   = tid & 127;
    const int oh_i = (tid >> 7) & 1;
    const int odq  = tid >> 8;            // 0..1
    const int oh   = (blockIdx.x << 1) | oh_i;
    const int od0  = (blockIdx.y << 3) | (odq << 2);   // first of 4 od
    const int n    = blockIdx.z;

    // ---- fill e: 2*8*3*11 = 528 items ----
    for (int t = tid; t < 528; t += 512) {
        int q = t;
        int eoh = q / 264;  q -= eoh * 264;
        int eod = q / 33;   q -= eod * 33;
        int c   = q / 11;
        int xi  = q - c * 11;
        int d_ = (blockIdx.y << 3) + eod + CROP0;
        int h_ = ((blockIdx.x << 1) | eoh) + CROP0;
        int zi0, zi1, yi0, yi1;
        float zw, yw;
        resize_coord(d_, zi0, zi1, zw);
        resize_coord(h_, yi0, yi1, yw);
        const float* f = fields + c * (FSZ*FSZ*FSZ);
        float v = f[zi0*121 + yi0*11 + xi] * ((1.0f-zw)*(1.0f-yw))
                + f[zi0*121 + yi1*11 + xi] * ((1.0f-zw)*yw)
                + f[zi1*121 + yi0*11 + xi] * (zw*(1.0f-yw))
                + f[zi1*121 + yi1*11 + xi] * (zw*yw);
        e[eoh][eod][c][xi] = v * 80.0f;   // pre-scaled to voxel units
    }
    __syncthreads();

    const int w_ = ow + CROP0;
    const int h_ = oh + CROP0;

    const float x = fmaf(2.0f * (float)w_ + 1.0f, 1.0f / (float)VD, -1.0f);
    const float y = fmaf(2.0f * (float)h_ + 1.0f, 1.0f / (float)VD, -1.0f);

    // x-knot lerp params (shared by all 4 outputs)
    int xi0, xi1; float xw;
    resize_coord(w_, xi0, xi1, xw);

    const float* th = theta + n*12;
    // constant (x,y) parts of the affine, pre-unnormalized: 80*g + 79.5
    const float cx = fmaf(th[0]*x + th[1]*y + th[3], 80.0f, 79.5f);
    const float cy = fmaf(th[4]*x + th[5]*y + th[7], 80.0f, 79.5f);
    const float cz = fmaf(th[8]*x + th[9]*y + th[11], 80.0f, 79.5f);
    const float tz0 = th[2] * 80.0f, tz1 = th[6] * 80.0f, tz2 = th[10] * 80.0f;

    const float* v = vol + (size_t)n * (VD*VD*VD);

    int   off[ODQ][4];                 // row byte-element offsets
    int   xA[ODQ], xB[ODQ];
    float WX0[ODQ], WX1[ODQ], WY0[ODQ], WY1[ODQ], WZ0[ODQ], WZ1[ODQ];

    #pragma unroll
    for (int k = 0; k < ODQ; ++k) {
        const int od = od0 + k;
        const int d_ = od + CROP0;
        const float z = fmaf(2.0f * (float)d_ + 1.0f, 1.0f / (float)VD, -1.0f);
        const float* ek = &e[oh_i][(odq << 2) + k][0][0];
        const float d80x = ek[      xi0] + (ek[      xi1] - ek[      xi0]) * xw;
        const float d80y = ek[12  + xi0] + (ek[12  + xi1] - ek[12  + xi0]) * xw;
        const float d80z = ek[24  + xi0] + (ek[24  + xi1] - ek[24  + xi0]) * xw;

        const float xs = fmaf(tz0, z, cx) + d80x;
        const float ys = fmaf(tz1, z, cy) + d80y;
        const float zs = fmaf(tz2, z, cz) + d80z;

        const float x0f = floorf(xs), y0f = floorf(ys), z0f = floorf(zs);
        const float fx = xs - x0f, fy = ys - y0f, fz = zs - z0f;
        const int ix0 = (int)x0f, iy0 = (int)y0f, iz0 = (int)z0f;
        const int ix1 = ix0 + 1,  iy1 = iy0 + 1,  iz1 = iz0 + 1;

        WX0[k] = ((unsigned)ix0 < (unsigned)VD) ? (1.0f - fx) : 0.0f;
        WX1[k] = ((unsigned)ix1 < (unsigned)VD) ? fx          : 0.0f;
        WY0[k] = ((unsigned)iy0 < (unsigned)VD) ? (1.0f - fy) : 0.0f;
        WY1[k] = ((unsigned)iy1 < (unsigned)VD) ? fy          : 0.0f;
        WZ0[k] = ((unsigned)iz0 < (unsigned)VD) ? (1.0f - fz) : 0.0f;
        WZ1[k] = ((unsigned)iz1 < (unsigned)VD) ? fz          : 0.0f;

        const int xc0 = min(max(ix0, 0), VD-1), xc1 = min(max(ix1, 0), VD-1);
        const int yc0 = min(max(iy0, 0), VD-1), yc1 = min(max(iy1, 0), VD-1);
        const int zc0 = min(max(iz0, 0), VD-1), zc1 = min(max(iz1, 0), VD-1);

        off[k][0] = (zc0*VD + yc0)*VD;
        off[k][1] = (zc0*VD + yc1)*VD;
        off[k][2] = (zc1*VD + yc0)*VD;
        off[k][3] = (zc1*VD + yc1)*VD;
        xA[k] = xc0; xB[k] = xc1;
    }

    // issue all 32 loads (independent -> compiler clusters them, deep MLP)
    float t00a[ODQ], t00b[ODQ], t01a[ODQ], t01b[ODQ];
    float t10a[ODQ], t10b[ODQ], t11a[ODQ], t11b[ODQ];
    #pragma unroll
    for (int k = 0; k < ODQ; ++k) {
        t00a[k] = v[off[k][0] + xA[k]];  t00b[k] = v[off[k][0] + xB[k]];
        t01a[k] = v[off[k][1] + xA[k]];  t01b[k] = v[off[k][1] + xB[k]];
        t10a[k] = v[off[k][2] + xA[k]];  t10b[k] = v[off[k][2] + xB[k]];
        t11a[k] = v[off[k][3] + xA[k]];  t11b[k] = v[off[k][3] + xB[k]];
    }

    #pragma unroll
    for (int k = 0; k < ODQ; ++k) {
        const float r00 = t00a[k]*WX0[k] + t00b[k]*WX1[k];
        const float r01 = t01a[k]*WX0[k] + t01b[k]*WX1[k];
        const float r10 = t10a[k]*WX0[k] + t10b[k]*WX1[k];
        const float r11 = t11a[k]*WX0[k] + t11b[k]*WX1[k];
        const float r = (r00*WY0[k] + r01*WY1[k])*WZ0[k]
                      + (r10*WY0[k] + r11*WY1[k])*WZ1[k];
        const int od = od0 + k;
        __builtin_nontemporal_store(
            r, &out[(((size_t)n*OD + od)*OD + oh)*OD + ow]);
    }
}

// ---------------------------------------------------------------------------
extern "C" void kernel_launch(void* const* d_in, const int* in_sizes, int n_in,
                              void* d_out, int out_size, void* d_ws, size_t ws_size,
                              hipStream_t stream) {
    const float* vol   = (const float*)d_in[0];
    const float* rot   = (const float*)d_in[1];
    const float* scale = (const float*)d_in[2];
    const float* shift = (const float*)d_in[3];
    const float* dz    = (const float*)d_in[4];
    const float* dy    = (const float*)d_in[5];
    const float* dx    = (const float*)d_in[6];
    float* out = (float*)d_out;

    float* ws     = (float*)d_ws;
    float* theta  = ws;         // 4*12 = 48 floats
    float* fields = ws + 48;    // 3*1331 floats

    prep_kernel<<<4, 256, 0, stream>>>(rot, scale, shift, dz, dy, dx,
                                       theta, fields);
    dim3 grid(OD/2, OD/8, NBATCH);
    sample_kernel<<<grid, 512, 0, stream>>>(vol, theta, fields, out);
}